// Round 26
// baseline (40.283 us; speedup 1.0000x reference)
//
#include <hip/hip_runtime.h>
#include <hip/hip_bf16.h>
#include <stdint.h>

#define N_ 2
#define C_ 256
#define SP 512
#define H1 128
#define H2 64
#define H3 32
#define NTILE 1056     // 528 triangular u-tiles x 2 batches
#define GRID 256

using f32x4 = __attribute__((ext_vector_type(4))) float;
using u32x4 = __attribute__((ext_vector_type(4))) unsigned int;
using s16x8 = __attribute__((ext_vector_type(8))) short;

__device__ __forceinline__ uint32_t f2bf_rne(float x) {
    uint32_t u = __builtin_bit_cast(uint32_t, x);
    return (u + 0x7FFFu + ((u >> 16) & 1u)) >> 16;
}
__device__ __forceinline__ float bf2f(uint32_t h) {
    return __builtin_bit_cast(float, h << 16);
}
// compiler-fused v_cvt_pk_bf16_f32 path (m240: casts, not inline asm).
// __hip_bfloat162 is not trivially copyable -> memcpy, not bit_cast (R18 fix).
__device__ __forceinline__ uint32_t pkbf(float a, float b) {
    __hip_bfloat162 h = __float22bfloat162_rn(make_float2(a, b));
    uint32_t r;
    __builtin_memcpy(&r, &h, 4);
    return r;
}
__device__ __forceinline__ uint16_t bf1(float a) {
    __hip_bfloat16 h = __float2bfloat16(a);
    uint16_t r;
    __builtin_memcpy(&r, &h, 2);
    return r;
}
__device__ __forceinline__ uint32_t pack_hi2(uint32_t u0, uint32_t u1) {
    return (u0 >> 16) | (u1 & 0xFFFF0000u);          // {u1.hi, u0.hi}
}
__device__ __forceinline__ f32x4 ntload4(const float* p) {
    return __builtin_nontemporal_load((const f32x4*)p);
}

// tau -> (n, iBase, jBase) over the bi<=bj triangle of 32x32 chunk pairs
__device__ __forceinline__ void unrank_tile(int tau, int& n, int& iBase, int& jBase)
{
    int nn = (tau >= 528) ? 1 : 0;
    int u = tau - nn * 528;
    int bi = (int)((65.0f - sqrtf(4225.0f - 8.0f * (float)u)) * 0.5f);
    int s = bi * (65 - bi) / 2;
    while (s > u) { --bi; s = bi * (65 - bi) / 2; }
    while (u - s >= 32 - bi) { ++bi; s = bi * (65 - bi) / 2; }
    int bj = bi + (u - s);
    n = nn; iBase = bi * 16; jBase = bj * 16;
}

// R25 precompA (MFMA-ized, kept): A = points^T @ W0 (+0.5*b0) via 3-product
// split-bf16 MFMA; 64 blocks x 8 waves; coalesced loads/stores; fused W-prep.
__global__ __launch_bounds__(512) void k_precompA(
    const float* __restrict__ points, const float* __restrict__ W0,
    const float* __restrict__ b0,
    const float* __restrict__ W1, const float* __restrict__ W2,
    float* __restrict__ A,
    short* __restrict__ W1Th, short* __restrict__ W2Th, short* __restrict__ W2Tl,
    float* __restrict__ accum)
{
    int t = threadIdx.x;
    int b = blockIdx.x;                              // 64 blocks
    if (b == 0 && t < 4) accum[t] = 0.0f;            // num, den, cnt, pad
    int l = t & 63, w = t >> 6;                      // 8 waves
    int lc = l & 15, kg = l >> 4;
    int rBase = b * 16;                              // A-rows rBase..rBase+15
    int n = rBase >> 9;                              // uniform per block
    int iRow = (rBase & (SP - 1)) + lc;
    const float* pb = points + (size_t)n * C_ * SP + iRow;   // + c*SP
    int hcol = w * 16 + lc;                          // H1 column for B/D

    f32x4 acc = {0.0f, 0.0f, 0.0f, 0.0f};
#pragma unroll
    for (int ks = 0; ks < 8; ++ks) {
        int c0 = ks * 32 + kg * 8;
        float xs[8];
#pragma unroll
        for (int e = 0; e < 8; ++e)
            xs[e] = pb[(size_t)(c0 + e) * SP];       // coalesced across lc
        u32x4 ah, al;
#pragma unroll
        for (int p = 0; p < 4; ++p) {
            uint32_t u0 = __builtin_bit_cast(uint32_t, xs[2 * p]);
            uint32_t u1 = __builtin_bit_cast(uint32_t, xs[2 * p + 1]);
            ah[p] = pack_hi2(u0, u1);                // trunc hi
            float l0 = xs[2 * p]     - bf2f(u0 >> 16);
            float l1 = xs[2 * p + 1] - bf2f(u1 >> 16);
            al[p] = pkbf(l0, l1);                    // rne lo
        }
        s16x8 ahi = __builtin_bit_cast(s16x8, ah);
        s16x8 alo = __builtin_bit_cast(s16x8, al);
        float ws[8];
#pragma unroll
        for (int e = 0; e < 8; ++e)
            ws[e] = W0[(size_t)(c0 + e) * H1 + hcol];
        u32x4 bh, bl;
#pragma unroll
        for (int p = 0; p < 4; ++p) {
            uint32_t u0 = __builtin_bit_cast(uint32_t, ws[2 * p]);
            uint32_t u1 = __builtin_bit_cast(uint32_t, ws[2 * p + 1]);
            bh[p] = pack_hi2(u0, u1);
            float l0 = ws[2 * p]     - bf2f(u0 >> 16);
            float l1 = ws[2 * p + 1] - bf2f(u1 >> 16);
            bl[p] = pkbf(l0, l1);
        }
        s16x8 bhi = __builtin_bit_cast(s16x8, bh);
        s16x8 blo = __builtin_bit_cast(s16x8, bl);
        acc = __builtin_amdgcn_mfma_f32_16x16x32_bf16(ahi, blo, acc, 0, 0, 0);
        acc = __builtin_amdgcn_mfma_f32_16x16x32_bf16(alo, bhi, acc, 0, 0, 0);
        acc = __builtin_amdgcn_mfma_f32_16x16x32_bf16(ahi, bhi, acc, 0, 0, 0);
    }
    float bv = 0.5f * b0[hcol];
#pragma unroll
    for (int r = 0; r < 4; ++r)                      // D: row=kg*4+r, col=lc
        A[(size_t)(rBase + kg * 4 + r) * H1 + hcol] = acc[r] + bv;

    // ---- fused W-prep (swizzled for conflict-free frag reads) ----
    int gid = b * 512 + t;
    int gstride = 64 * 512;
    for (int idx = gid; idx < H2 * H1; idx += gstride) {      // W1 hi (rne) only
        int col = idx >> 7, k = idx & 127;
        int sidx = col * 128 + ((((k >> 3) ^ (col & 15)) << 3) | (k & 7));
        W1Th[sidx] = (short)f2bf_rne(W1[k * H2 + col]);
    }
    for (int idx = gid; idx < H3 * H2; idx += gstride) {      // W2 hi (rne) only
        int col = idx >> 6, k = idx & 63;
        int sidx = col * 64 + ((((k >> 3) ^ (col & 7)) << 3) | (k & 7));
        W2Th[sidx] = (short)f2bf_rne(W2[k * H3 + col]);
    }
}

// R26 = R25 + TAIL DIET (funded by accuracy budget, 0.0098 of 0.027 used):
//  - layer 4 in-register via shfl_xor over 16-lane groups (x3 LDS + layer-4
//    MFMA + bw3 removed; fp32 dot is MORE accurate). R21 proved R16's
//    regression was GRID=512, not this variant.
//  - layer 3 single-product (W2 rne-hi only; W2-lo dropped): 8 fewer MFMAs
//    + half the W2 L1 traffic; +~2-4e-3 absmax, within budget.
// GRID=256 final; static schedule final; two dispatches final.
// Launch-bounds history: (512,8)/(512,4) spill; keep (512,2).
__global__ __launch_bounds__(512, 2) void k_main(
    const float* __restrict__ A,
    const short* __restrict__ wtab,     // W1Th(16384B)|W2Th(4096B)
    const float* __restrict__ b1, const float* __restrict__ b2,
    const float* __restrict__ W3, const float* __restrict__ b3,
    const float* __restrict__ heat, const float* __restrict__ mask,
    const float* __restrict__ pos,
    float* __restrict__ pred, float* __restrict__ accum, float* __restrict__ loss)
{
    // LDS: Abuf[2][16KB] | x2 8w x 2m x 2KB | zb[2][1088] | rb
    __shared__ __align__(16) char smem[32768 + 32768 + 2176 + 64];
    int t = threadIdx.x;
    int bid = blockIdx.x;
    int l = t & 63, w = t >> 6;
    int lc = l & 15, kg = l >> 4;
    char* x2b = smem + 32768 + w * 4096;             // [m][16][128B] swz, per-wave
    char* zbB = smem + 65536;
    float* rb = (float*)(smem + 65536 + 2176);

    const short* lw1h = wtab;                        // global, L1-resident
    const short* lw2h = wtab + 8192;

    int rST = t >> 5, segST = t & 31;                // staging: row 0..15, 16B seg

    float w3a = W3[lc], w3b = W3[16 + lc];
    float b3v = b3[0];

    float num = 0.0f, den = 0.0f;

    // ---- prologue: stage first tile into buf 0 ----
    {
        int n0, ib0, jb0; unrank_tile(bid, n0, ib0, jb0);
        const float* Ab = A + (size_t)n0 * SP * H1;
        f32x4 va = ntload4(Ab + (size_t)(ib0 + rST) * H1 + segST * 4);
        f32x4 vb = ntload4(Ab + (size_t)(jb0 + rST) * H1 + segST * 4);
        *(f32x4*)(smem + rST * 512 + ((segST ^ rST) << 4)) = va;
        *(f32x4*)(smem + 8192 + rST * 512 + ((segST ^ rST) << 4)) = vb;
    }
    __syncthreads();

    int cur = 0, itp = 0;
    for (int tau = bid; tau < NTILE; tau += GRID, cur ^= 1, itp ^= 1) {
        int n, iBase, jBase; unrank_tile(tau, n, iBase, jBase);
        char* aiA = smem + cur * 16384;
        char* ajA = aiA + 8192;
        float* zb = (float*)(zbB + itp * 1088);

        // ---- issue next-tile stage loads (consumed after compute) ----
        bool hn = (tau + GRID < NTILE);
        f32x4 sva, svb;
        if (hn) {
            int n1, ib1, jb1; unrank_tile(tau + GRID, n1, ib1, jb1);
            const float* Ab1 = A + (size_t)n1 * SP * H1;
            sva = ntload4(Ab1 + (size_t)(ib1 + rST) * H1 + segST * 4);
            svb = ntload4(Ab1 + (size_t)(jb1 + rST) * H1 + segST * 4);
        }

        // ---- epilogue prefetch for current tile (hides under compute) ----
        int pr = (t & 255) >> 4, pc = t & 15;
        size_t idx_e = (t < 256)
            ? ((size_t)n * SP + iBase + pr) * SP + (jBase + pc)
            : ((size_t)n * SP + jBase + pr) * SP + (iBase + pc);
        float tg_e = __builtin_nontemporal_load(heat + idx_e);
        float mk_e = __builtin_nontemporal_load(mask + idx_e);
        float pm_e = __builtin_nontemporal_load(pos + idx_e);

        // ---- layer 2: acc[m][cf] = cvt_bf16(relu(Ai+Aj)) @ W1hi + b1 ----
        f32x4 acc[2][4];
#pragma unroll
        for (int cf = 0; cf < 4; ++cf) {
            float bv = b1[cf * 16 + lc];
            acc[0][cf] = (f32x4){bv, bv, bv, bv};
            acc[1][cf] = (f32x4){bv, bv, bv, bv};
        }
#pragma unroll
        for (int ks = 0; ks < 4; ++ks) {
            int g0 = ks * 8 + kg * 2;
            f32x4 aj0 = *(const f32x4*)(ajA + lc * 512 + ((g0 ^ lc) << 4));
            f32x4 aj1 = *(const f32x4*)(ajA + lc * 512 + (((g0 + 1) ^ lc) << 4));
#pragma unroll
            for (int m = 0; m < 2; ++m) {
                int rl = 2 * w + m;                  // wave-uniform -> LDS broadcast
                f32x4 ai0 = *(const f32x4*)(aiA + rl * 512 + ((g0 ^ rl) << 4));
                f32x4 ai1 = *(const f32x4*)(aiA + rl * 512 + (((g0 + 1) ^ rl) << 4));
                float xs[8];
#pragma unroll
                for (int e = 0; e < 4; ++e) {
                    xs[e]     = fmaxf(ai0[e] + aj0[e], 0.0f);
                    xs[4 + e] = fmaxf(ai1[e] + aj1[e], 0.0f);
                }
                u32x4 hw;
#pragma unroll
                for (int p = 0; p < 4; ++p)
                    hw[p] = pkbf(xs[2 * p], xs[2 * p + 1]);
                s16x8 ahi = __builtin_bit_cast(s16x8, hw);
#pragma unroll
                for (int cf = 0; cf < 4; ++cf) {
                    int boff = (cf * 16 + lc) * 128 + (((ks * 4 + kg) ^ lc) << 3);
                    s16x8 bhi = *(const s16x8*)(lw1h + boff);
                    acc[m][cf] = __builtin_amdgcn_mfma_f32_16x16x32_bf16(ahi, bhi, acc[m][cf], 0, 0, 0);
                }
            }
        }

        // ---- tail: X2 (both m) -> layer3 (1-product) -> layer4 via shfl ----
#pragma unroll
        for (int m = 0; m < 2; ++m) {
            char* x2 = x2b + m * 2048;
#pragma unroll
            for (int cf = 0; cf < 4; ++cf) {
                int g = cf * 2 + (lc >> 3);
#pragma unroll
                for (int r = 0; r < 4; ++r) {
                    int row = kg * 4 + r;
                    int off = row * 128 + ((g ^ (row & 7)) << 4) + (lc & 7) * 2;
                    *(uint16_t*)(x2 + off) = bf1(fmaxf(acc[m][cf][r], 0.0f));
                }
            }
        }
        f32x4 acc2[2][2];
#pragma unroll
        for (int cf = 0; cf < 2; ++cf) {
            float bv = b2[cf * 16 + lc];
            acc2[0][cf] = (f32x4){bv, bv, bv, bv};
            acc2[1][cf] = (f32x4){bv, bv, bv, bv};
        }
#pragma unroll
        for (int ks = 0; ks < 2; ++ks) {
#pragma unroll
            for (int m = 0; m < 2; ++m) {
                int aoff = lc * 128 + (((ks * 4 + kg) ^ (lc & 7)) << 4);
                s16x8 xa = *(const s16x8*)(x2b + m * 2048 + aoff);
#pragma unroll
                for (int cf = 0; cf < 2; ++cf) {
                    int b2off = (cf * 16 + lc) * 64 + (((ks * 4 + kg) ^ (lc & 7)) << 3);
                    s16x8 bh = *(const s16x8*)(lw2h + b2off);
                    acc2[m][cf] = __builtin_amdgcn_mfma_f32_16x16x32_bf16(xa, bh, acc2[m][cf], 0, 0, 0);
                }
            }
        }
        // layer 4: z[jpix=kg*4+r] = sum_lc relu(C2)*W3 ; 8 independent chains,
        // reduced across the 16-lane lc group (xor 1,2,4,8 stays in-group)
        float zr[2][4];
#pragma unroll
        for (int m = 0; m < 2; ++m)
#pragma unroll
            for (int r = 0; r < 4; ++r)
                zr[m][r] = fmaxf(acc2[m][0][r], 0.0f) * w3a
                         + fmaxf(acc2[m][1][r], 0.0f) * w3b;
#pragma unroll
        for (int off = 1; off < 16; off <<= 1) {
#pragma unroll
            for (int m = 0; m < 2; ++m)
#pragma unroll
                for (int r = 0; r < 4; ++r)
                    zr[m][r] += __shfl_xor(zr[m][r], off, 64);
        }
#pragma unroll
        for (int m = 0; m < 2; ++m) {
            float zsel = zr[m][0];
            zsel = (lc == 1) ? zr[m][1] : zsel;
            zsel = (lc == 2) ? zr[m][2] : zsel;
            zsel = (lc == 3) ? zr[m][3] : zsel;
            if (lc < 4)
                zb[(2 * w + m) * 17 + kg * 4 + lc] = zsel + b3v;
        }

        // ---- write next tile's stage into alternate buffer ----
        if (hn) {
            char* Aalt = smem + (cur ^ 1) * 16384;
            *(f32x4*)(Aalt + rST * 512 + ((segST ^ rST) << 4)) = sva;
            *(f32x4*)(Aalt + 8192 + rST * 512 + ((segST ^ rST) << 4)) = svb;
        }
        __syncthreads();   // zb ready + next A ready

        // ---- load-free epilogue: stores + fused BCE from prefetched regs ----
        if (t < 256) {                               // primary 16x16, j >= i
            int i = iBase + pr, j = jBase + pc;
            if (j >= i) {
                float z = zb[pr * 17 + pc];
                __builtin_nontemporal_store(z, pred + idx_e);
                float bce = fmaxf(z, 0.0f) - z * tg_e + __logf(1.0f + __expf(-fabsf(z)));
                num += bce * mk_e * pm_e;
                den += pm_e;
            }
        } else {                                     // mirror 16x16, J > I
            int J = jBase + pr, I = iBase + pc;
            if (J > I) {
                float z = zb[pc * 17 + pr];
                __builtin_nontemporal_store(z, pred + idx_e);
                float bce = fmaxf(z, 0.0f) - z * tg_e + __logf(1.0f + __expf(-fabsf(z)));
                num += bce * mk_e * pm_e;
                den += pm_e;
            }
        }
    }

    // ---- block loss reduction -> one atomic pair; last block finalizes ----
#pragma unroll
    for (int off = 32; off > 0; off >>= 1) {
        num += __shfl_down(num, off, 64);
        den += __shfl_down(den, off, 64);
    }
    if (l == 0) { rb[w] = num; rb[8 + w] = den; }
    __syncthreads();
    if (t == 0) {
        float sn = 0.0f, sd = 0.0f;
#pragma unroll
        for (int q = 0; q < 8; ++q) { sn += rb[q]; sd += rb[8 + q]; }
        atomicAdd(&accum[0], sn);
        atomicAdd(&accum[1], sd);
        __threadfence();                             // publish before counting
        unsigned done = atomicAdd((unsigned*)&accum[2], 1u);
        if (done == GRID - 1) {                      // last block: finalize loss
            float fn = atomicAdd(&accum[0], 0.0f);   // coherent RMW read
            float fd = atomicAdd(&accum[1], 0.0f);
            loss[0] = fn / fd;
        }
    }
}

extern "C" void kernel_launch(void* const* d_in, const int* in_sizes, int n_in,
                              void* d_out, int out_size, void* d_ws, size_t ws_size,
                              hipStream_t stream)
{
    const float* points = (const float*)d_in[0];
    const float* heat   = (const float*)d_in[1];
    const float* mask   = (const float*)d_in[2];
    const float* pos    = (const float*)d_in[3];
    const float* W0     = (const float*)d_in[4];
    const float* b0     = (const float*)d_in[5];
    const float* W1     = (const float*)d_in[6];
    const float* b1     = (const float*)d_in[7];
    const float* W2     = (const float*)d_in[8];
    const float* b2     = (const float*)d_in[9];
    const float* W3     = (const float*)d_in[10];
    const float* b3     = (const float*)d_in[11];

    float* pred = (float*)d_out;                        // (2,512,512)
    float* loss = pred + (size_t)N_ * SP * SP;          // scalar

    char* ws = (char*)d_ws;
    float* accum = (float*)ws;                          // [0]=num,[1]=den,[2]=cnt
    float* A     = (float*)(ws + 256);                  // 512 KiB
    short* W1Th  = (short*)(ws + 256 + 524288);         // wtab contiguous:
    short* W2Th  = (short*)(ws + 256 + 524288 + 16384); //   W1Th|W2Th
    short* W2Tl  = (short*)(ws + 256 + 524288 + 20480); //   (unused slot kept)

    k_precompA<<<64, 512, 0, stream>>>(points, W0, b0, W1, W2, A,
                                       W1Th, W2Th, W2Tl, accum);
    k_main<<<GRID, 512, 0, stream>>>(
        A, W1Th, b1, b2, W3, b3, heat, mask, pos, pred, accum, loss);
}

// Round 27
// 38.972 us; speedup vs baseline: 1.0336x; 1.0336x over previous
//
#include <hip/hip_runtime.h>
#include <hip/hip_bf16.h>
#include <stdint.h>

#define N_ 2
#define C_ 256
#define SP 512
#define H1 128
#define H2 64
#define H3 32
#define NTILE 1056     // 528 triangular u-tiles x 2 batches
#define GRID 256

using f32x4 = __attribute__((ext_vector_type(4))) float;
using u32x4 = __attribute__((ext_vector_type(4))) unsigned int;
using s16x8 = __attribute__((ext_vector_type(8))) short;

__device__ __forceinline__ uint32_t f2bf_rne(float x) {
    uint32_t u = __builtin_bit_cast(uint32_t, x);
    return (u + 0x7FFFu + ((u >> 16) & 1u)) >> 16;
}
__device__ __forceinline__ float bf2f(uint32_t h) {
    return __builtin_bit_cast(float, h << 16);
}
// compiler-fused v_cvt_pk_bf16_f32 path (m240: casts, not inline asm).
// __hip_bfloat162 is not trivially copyable -> memcpy, not bit_cast (R18 fix).
__device__ __forceinline__ uint32_t pkbf(float a, float b) {
    __hip_bfloat162 h = __float22bfloat162_rn(make_float2(a, b));
    uint32_t r;
    __builtin_memcpy(&r, &h, 4);
    return r;
}
__device__ __forceinline__ uint16_t bf1(float a) {
    __hip_bfloat16 h = __float2bfloat16(a);
    uint16_t r;
    __builtin_memcpy(&r, &h, 2);
    return r;
}
__device__ __forceinline__ uint32_t pack_hi2(uint32_t u0, uint32_t u1) {
    return (u0 >> 16) | (u1 & 0xFFFF0000u);          // {u1.hi, u0.hi}
}
__device__ __forceinline__ f32x4 ntload4(const float* p) {
    return __builtin_nontemporal_load((const f32x4*)p);
}

// tau -> (n, iBase, jBase) over the bi<=bj triangle of 32x32 chunk pairs
__device__ __forceinline__ void unrank_tile(int tau, int& n, int& iBase, int& jBase)
{
    int nn = (tau >= 528) ? 1 : 0;
    int u = tau - nn * 528;
    int bi = (int)((65.0f - sqrtf(4225.0f - 8.0f * (float)u)) * 0.5f);
    int s = bi * (65 - bi) / 2;
    while (s > u) { --bi; s = bi * (65 - bi) / 2; }
    while (u - s >= 32 - bi) { ++bi; s = bi * (65 - bi) / 2; }
    int bj = bi + (u - s);
    n = nn; iBase = bi * 16; jBase = bj * 16;
}

// R25 precompA (MFMA-ized): A = points^T @ W0 (+0.5*b0) via 3-product
// split-bf16 MFMA; 64 blocks x 8 waves; coalesced loads/stores; fused W-prep.
__global__ __launch_bounds__(512) void k_precompA(
    const float* __restrict__ points, const float* __restrict__ W0,
    const float* __restrict__ b0,
    const float* __restrict__ W1, const float* __restrict__ W2,
    float* __restrict__ A,
    short* __restrict__ W1Th, short* __restrict__ W2Th, short* __restrict__ W2Tl,
    float* __restrict__ accum)
{
    int t = threadIdx.x;
    int b = blockIdx.x;                              // 64 blocks
    if (b == 0 && t < 4) accum[t] = 0.0f;            // num, den, cnt, pad
    int l = t & 63, w = t >> 6;                      // 8 waves
    int lc = l & 15, kg = l >> 4;
    int rBase = b * 16;                              // A-rows rBase..rBase+15
    int n = rBase >> 9;                              // uniform per block
    int iRow = (rBase & (SP - 1)) + lc;
    const float* pb = points + (size_t)n * C_ * SP + iRow;   // + c*SP
    int hcol = w * 16 + lc;                          // H1 column for B/D

    f32x4 acc = {0.0f, 0.0f, 0.0f, 0.0f};
#pragma unroll
    for (int ks = 0; ks < 8; ++ks) {
        int c0 = ks * 32 + kg * 8;
        float xs[8];
#pragma unroll
        for (int e = 0; e < 8; ++e)
            xs[e] = pb[(size_t)(c0 + e) * SP];       // coalesced across lc
        u32x4 ah, al;
#pragma unroll
        for (int p = 0; p < 4; ++p) {
            uint32_t u0 = __builtin_bit_cast(uint32_t, xs[2 * p]);
            uint32_t u1 = __builtin_bit_cast(uint32_t, xs[2 * p + 1]);
            ah[p] = pack_hi2(u0, u1);                // trunc hi
            float l0 = xs[2 * p]     - bf2f(u0 >> 16);
            float l1 = xs[2 * p + 1] - bf2f(u1 >> 16);
            al[p] = pkbf(l0, l1);                    // rne lo
        }
        s16x8 ahi = __builtin_bit_cast(s16x8, ah);
        s16x8 alo = __builtin_bit_cast(s16x8, al);
        float ws[8];
#pragma unroll
        for (int e = 0; e < 8; ++e)
            ws[e] = W0[(size_t)(c0 + e) * H1 + hcol];
        u32x4 bh, bl;
#pragma unroll
        for (int p = 0; p < 4; ++p) {
            uint32_t u0 = __builtin_bit_cast(uint32_t, ws[2 * p]);
            uint32_t u1 = __builtin_bit_cast(uint32_t, ws[2 * p + 1]);
            bh[p] = pack_hi2(u0, u1);
            float l0 = ws[2 * p]     - bf2f(u0 >> 16);
            float l1 = ws[2 * p + 1] - bf2f(u1 >> 16);
            bl[p] = pkbf(l0, l1);
        }
        s16x8 bhi = __builtin_bit_cast(s16x8, bh);
        s16x8 blo = __builtin_bit_cast(s16x8, bl);
        acc = __builtin_amdgcn_mfma_f32_16x16x32_bf16(ahi, blo, acc, 0, 0, 0);
        acc = __builtin_amdgcn_mfma_f32_16x16x32_bf16(alo, bhi, acc, 0, 0, 0);
        acc = __builtin_amdgcn_mfma_f32_16x16x32_bf16(ahi, bhi, acc, 0, 0, 0);
    }
    float bv = 0.5f * b0[hcol];
#pragma unroll
    for (int r = 0; r < 4; ++r)                      // D: row=kg*4+r, col=lc
        A[(size_t)(rBase + kg * 4 + r) * H1 + hcol] = acc[r] + bv;

    // ---- fused W-prep (swizzled for conflict-free frag reads) ----
    int gid = b * 512 + t;
    int gstride = 64 * 512;
    for (int idx = gid; idx < H2 * H1; idx += gstride) {      // W1 hi (rne) only
        int col = idx >> 7, k = idx & 127;
        int sidx = col * 128 + ((((k >> 3) ^ (col & 15)) << 3) | (k & 7));
        W1Th[sidx] = (short)f2bf_rne(W1[k * H2 + col]);
    }
    for (int idx = gid; idx < H3 * H2; idx += gstride) {      // W2 hi+lo
        int col = idx >> 6, k = idx & 63;
        float wv = W2[k * H3 + col];
        uint32_t h = f2bf_rne(wv);
        int sidx = col * 64 + ((((k >> 3) ^ (col & 7)) << 3) | (k & 7));
        W2Th[sidx] = (short)h;
        W2Tl[sidx] = (short)f2bf_rne(wv - bf2f(h));
    }
}

// FINAL (R27 = R25, best measured 39.1us): persistent 2-dispatch structure.
// Settled by measurement: GRID=256 (512 regressed, R16/R21); static schedule
// (work-steal regressed, R23); two dispatches (grid.sync regressed, R22);
// R24/R26 tail variants neutral/regressed -> per-m x2/x3 tail with layer-4
// MFMA kept. k_main is latency-structure bound (~27us, all pipes <30% busy).
// Launch-bounds history: (512,8)/(512,4) spill; keep (512,2).
__global__ __launch_bounds__(512, 2) void k_main(
    const float* __restrict__ A,
    const short* __restrict__ wtab,     // W1Th(16384B)|W2Th(4096B)|W2Tl(4096B)
    const float* __restrict__ b1, const float* __restrict__ b2,
    const float* __restrict__ W3, const float* __restrict__ b3,
    const float* __restrict__ heat, const float* __restrict__ mask,
    const float* __restrict__ pos,
    float* __restrict__ pred, float* __restrict__ accum, float* __restrict__ loss)
{
    // LDS: Abuf[2][16KB] | x2 8w x 2m x 2KB | x3 8w x 2m x 1KB | zb[2][1088] | rb
    __shared__ __align__(16) char smem[32768 + 32768 + 16384 + 2176 + 64];
    int t = threadIdx.x;
    int bid = blockIdx.x;
    int l = t & 63, w = t >> 6;
    int lc = l & 15, kg = l >> 4;
    char* x2b = smem + 32768 + w * 4096;             // [m][16][128B] swz, per-wave
    char* x3b = smem + 65536 + w * 2048;             // [m][16][64B] swz, per-wave
    char* zbB = smem + 81920;
    float* rb = (float*)(smem + 81920 + 2176);

    const short* lw1h = wtab;                        // global, L1-resident
    const short* lw2h = wtab + 8192;
    const short* lw2l = wtab + 10240;

    int rST = t >> 5, segST = t & 31;                // staging: row 0..15, 16B seg

    // W3 broadcast B-frag (bf16 rne) + b3 (once per block)
    s16x8 bw3;
    {
        f32x4 wa = *(const f32x4*)(W3 + kg * 8);
        f32x4 wb = *(const f32x4*)(W3 + kg * 8 + 4);
        u32x4 wp;
        wp[0] = pkbf(wa[0], wa[1]);
        wp[1] = pkbf(wa[2], wa[3]);
        wp[2] = pkbf(wb[0], wb[1]);
        wp[3] = pkbf(wb[2], wb[3]);
        bw3 = __builtin_bit_cast(s16x8, wp);
    }
    float b3v = b3[0];

    float num = 0.0f, den = 0.0f;

    // ---- prologue: stage first tile into buf 0 ----
    {
        int n0, ib0, jb0; unrank_tile(bid, n0, ib0, jb0);
        const float* Ab = A + (size_t)n0 * SP * H1;
        f32x4 va = ntload4(Ab + (size_t)(ib0 + rST) * H1 + segST * 4);
        f32x4 vb = ntload4(Ab + (size_t)(jb0 + rST) * H1 + segST * 4);
        *(f32x4*)(smem + rST * 512 + ((segST ^ rST) << 4)) = va;
        *(f32x4*)(smem + 8192 + rST * 512 + ((segST ^ rST) << 4)) = vb;
    }
    __syncthreads();

    int cur = 0, itp = 0;
    for (int tau = bid; tau < NTILE; tau += GRID, cur ^= 1, itp ^= 1) {
        int n, iBase, jBase; unrank_tile(tau, n, iBase, jBase);
        char* aiA = smem + cur * 16384;
        char* ajA = aiA + 8192;
        float* zb = (float*)(zbB + itp * 1088);

        // ---- issue next-tile stage loads (consumed after compute) ----
        bool hn = (tau + GRID < NTILE);
        f32x4 sva, svb;
        if (hn) {
            int n1, ib1, jb1; unrank_tile(tau + GRID, n1, ib1, jb1);
            const float* Ab1 = A + (size_t)n1 * SP * H1;
            sva = ntload4(Ab1 + (size_t)(ib1 + rST) * H1 + segST * 4);
            svb = ntload4(Ab1 + (size_t)(jb1 + rST) * H1 + segST * 4);
        }

        // ---- epilogue prefetch for current tile (hides under compute) ----
        int pr = (t & 255) >> 4, pc = t & 15;
        size_t idx_e = (t < 256)
            ? ((size_t)n * SP + iBase + pr) * SP + (jBase + pc)
            : ((size_t)n * SP + jBase + pr) * SP + (iBase + pc);
        float tg_e = __builtin_nontemporal_load(heat + idx_e);
        float mk_e = __builtin_nontemporal_load(mask + idx_e);
        float pm_e = __builtin_nontemporal_load(pos + idx_e);

        // ---- layer 2: acc[m][cf] = cvt_bf16(relu(Ai+Aj)) @ W1hi + b1 ----
        f32x4 acc[2][4];
#pragma unroll
        for (int cf = 0; cf < 4; ++cf) {
            float bv = b1[cf * 16 + lc];
            acc[0][cf] = (f32x4){bv, bv, bv, bv};
            acc[1][cf] = (f32x4){bv, bv, bv, bv};
        }
#pragma unroll
        for (int ks = 0; ks < 4; ++ks) {
            int g0 = ks * 8 + kg * 2;
            f32x4 aj0 = *(const f32x4*)(ajA + lc * 512 + ((g0 ^ lc) << 4));
            f32x4 aj1 = *(const f32x4*)(ajA + lc * 512 + (((g0 + 1) ^ lc) << 4));
#pragma unroll
            for (int m = 0; m < 2; ++m) {
                int rl = 2 * w + m;                  // wave-uniform -> LDS broadcast
                f32x4 ai0 = *(const f32x4*)(aiA + rl * 512 + ((g0 ^ rl) << 4));
                f32x4 ai1 = *(const f32x4*)(aiA + rl * 512 + (((g0 + 1) ^ rl) << 4));
                float xs[8];
#pragma unroll
                for (int e = 0; e < 4; ++e) {
                    xs[e]     = fmaxf(ai0[e] + aj0[e], 0.0f);
                    xs[4 + e] = fmaxf(ai1[e] + aj1[e], 0.0f);
                }
                u32x4 hw;
#pragma unroll
                for (int p = 0; p < 4; ++p)
                    hw[p] = pkbf(xs[2 * p], xs[2 * p + 1]);
                s16x8 ahi = __builtin_bit_cast(s16x8, hw);
#pragma unroll
                for (int cf = 0; cf < 4; ++cf) {
                    int boff = (cf * 16 + lc) * 128 + (((ks * 4 + kg) ^ lc) << 3);
                    s16x8 bhi = *(const s16x8*)(lw1h + boff);
                    acc[m][cf] = __builtin_amdgcn_mfma_f32_16x16x32_bf16(ahi, bhi, acc[m][cf], 0, 0, 0);
                }
            }
        }

        // ---- tail, both m interleaved: X2 -> layer3 -> X3 -> layer4 ----
#pragma unroll
        for (int m = 0; m < 2; ++m) {
            char* x2 = x2b + m * 2048;
#pragma unroll
            for (int cf = 0; cf < 4; ++cf) {
                int g = cf * 2 + (lc >> 3);
#pragma unroll
                for (int r = 0; r < 4; ++r) {
                    int row = kg * 4 + r;
                    int off = row * 128 + ((g ^ (row & 7)) << 4) + (lc & 7) * 2;
                    *(uint16_t*)(x2 + off) = bf1(fmaxf(acc[m][cf][r], 0.0f));
                }
            }
        }
        f32x4 acc2[2][2];
#pragma unroll
        for (int cf = 0; cf < 2; ++cf) {
            float bv = b2[cf * 16 + lc];
            acc2[0][cf] = (f32x4){bv, bv, bv, bv};
            acc2[1][cf] = (f32x4){bv, bv, bv, bv};
        }
#pragma unroll
        for (int ks = 0; ks < 2; ++ks) {
#pragma unroll
            for (int m = 0; m < 2; ++m) {
                int aoff = lc * 128 + (((ks * 4 + kg) ^ (lc & 7)) << 4);
                s16x8 xa = *(const s16x8*)(x2b + m * 2048 + aoff);
#pragma unroll
                for (int cf = 0; cf < 2; ++cf) {
                    int b2off = (cf * 16 + lc) * 64 + (((ks * 4 + kg) ^ (lc & 7)) << 3);
                    s16x8 bh = *(const s16x8*)(lw2h + b2off);
                    s16x8 bl = *(const s16x8*)(lw2l + b2off);
                    acc2[m][cf] = __builtin_amdgcn_mfma_f32_16x16x32_bf16(xa, bh, acc2[m][cf], 0, 0, 0);
                    acc2[m][cf] = __builtin_amdgcn_mfma_f32_16x16x32_bf16(xa, bl, acc2[m][cf], 0, 0, 0);
                }
            }
        }
#pragma unroll
        for (int m = 0; m < 2; ++m) {
            char* x3 = x3b + m * 1024;
#pragma unroll
            for (int cf = 0; cf < 2; ++cf) {
                int g = cf * 2 + (lc >> 3);
#pragma unroll
                for (int r = 0; r < 4; ++r) {
                    int row = kg * 4 + r;
                    int off = row * 64 + ((g ^ (row & 3)) << 4) + (lc & 7) * 2;
                    *(uint16_t*)(x3 + off) = bf1(fmaxf(acc2[m][cf][r], 0.0f));
                }
            }
        }
#pragma unroll
        for (int m = 0; m < 2; ++m) {
            int a4off = lc * 64 + ((kg ^ (lc & 3)) << 4);
            s16x8 x4 = *(const s16x8*)(x3b + m * 1024 + a4off);
            f32x4 acc3 = (f32x4){b3v, b3v, b3v, b3v};
            acc3 = __builtin_amdgcn_mfma_f32_16x16x32_bf16(x4, bw3, acc3, 0, 0, 0);
            if (lc == 0) {
#pragma unroll
                for (int r = 0; r < 4; ++r)
                    zb[(2 * w + m) * 17 + kg * 4 + r] = acc3[r];
            }
        }

        // ---- write next tile's stage into alternate buffer ----
        if (hn) {
            char* Aalt = smem + (cur ^ 1) * 16384;
            *(f32x4*)(Aalt + rST * 512 + ((segST ^ rST) << 4)) = sva;
            *(f32x4*)(Aalt + 8192 + rST * 512 + ((segST ^ rST) << 4)) = svb;
        }
        __syncthreads();   // zb ready + next A ready

        // ---- load-free epilogue: stores + fused BCE from prefetched regs ----
        if (t < 256) {                               // primary 16x16, j >= i
            int i = iBase + pr, j = jBase + pc;
            if (j >= i) {
                float z = zb[pr * 17 + pc];
                __builtin_nontemporal_store(z, pred + idx_e);
                float bce = fmaxf(z, 0.0f) - z * tg_e + __logf(1.0f + __expf(-fabsf(z)));
                num += bce * mk_e * pm_e;
                den += pm_e;
            }
        } else {                                     // mirror 16x16, J > I
            int J = jBase + pr, I = iBase + pc;
            if (J > I) {
                float z = zb[pc * 17 + pr];
                __builtin_nontemporal_store(z, pred + idx_e);
                float bce = fmaxf(z, 0.0f) - z * tg_e + __logf(1.0f + __expf(-fabsf(z)));
                num += bce * mk_e * pm_e;
                den += pm_e;
            }
        }
    }

    // ---- block loss reduction -> one atomic pair; last block finalizes ----
#pragma unroll
    for (int off = 32; off > 0; off >>= 1) {
        num += __shfl_down(num, off, 64);
        den += __shfl_down(den, off, 64);
    }
    if (l == 0) { rb[w] = num; rb[8 + w] = den; }
    __syncthreads();
    if (t == 0) {
        float sn = 0.0f, sd = 0.0f;
#pragma unroll
        for (int q = 0; q < 8; ++q) { sn += rb[q]; sd += rb[8 + q]; }
        atomicAdd(&accum[0], sn);
        atomicAdd(&accum[1], sd);
        __threadfence();                             // publish before counting
        unsigned done = atomicAdd((unsigned*)&accum[2], 1u);
        if (done == GRID - 1) {                      // last block: finalize loss
            float fn = atomicAdd(&accum[0], 0.0f);   // coherent RMW read
            float fd = atomicAdd(&accum[1], 0.0f);
            loss[0] = fn / fd;
        }
    }
}

extern "C" void kernel_launch(void* const* d_in, const int* in_sizes, int n_in,
                              void* d_out, int out_size, void* d_ws, size_t ws_size,
                              hipStream_t stream)
{
    const float* points = (const float*)d_in[0];
    const float* heat   = (const float*)d_in[1];
    const float* mask   = (const float*)d_in[2];
    const float* pos    = (const float*)d_in[3];
    const float* W0     = (const float*)d_in[4];
    const float* b0     = (const float*)d_in[5];
    const float* W1     = (const float*)d_in[6];
    const float* b1     = (const float*)d_in[7];
    const float* W2     = (const float*)d_in[8];
    const float* b2     = (const float*)d_in[9];
    const float* W3     = (const float*)d_in[10];
    const float* b3     = (const float*)d_in[11];

    float* pred = (float*)d_out;                        // (2,512,512)
    float* loss = pred + (size_t)N_ * SP * SP;          // scalar

    char* ws = (char*)d_ws;
    float* accum = (float*)ws;                          // [0]=num,[1]=den,[2]=cnt
    float* A     = (float*)(ws + 256);                  // 512 KiB
    short* W1Th  = (short*)(ws + 256 + 524288);         // wtab contiguous 24576B:
    short* W2Th  = (short*)(ws + 256 + 524288 + 16384); //   W1Th|W2Th|W2Tl
    short* W2Tl  = (short*)(ws + 256 + 524288 + 20480);

    k_precompA<<<64, 512, 0, stream>>>(points, W0, b0, W1, W2, A,
                                       W1Th, W2Th, W2Tl, accum);
    k_main<<<GRID, 512, 0, stream>>>(
        A, W1Th, b1, b2, W3, b3, heat, mask, pos, pred, accum, loss);
}